// Round 3
// baseline (610.152 us; speedup 1.0000x reference)
//
#include <hip/hip_runtime.h>
#include <math.h>

#define TT 256
#define NI 29
#define HH 128
#define NC 29
#define ROWS 16
#define PSTR 136   // fp16 plane stride: 128 + 8 pad -> ds_read_b128 2-way (free)

typedef _Float16 f16x8 __attribute__((ext_vector_type(8)));
typedef _Float16 f16x4 __attribute__((ext_vector_type(4)));
typedef float f32x4 __attribute__((ext_vector_type(4)));

__device__ __forceinline__ float fast_tanh(float x) {
    float ax = fabsf(x);
    float e = __builtin_amdgcn_exp2f(ax * -2.885390081777927f);
    float r = (1.0f - e) * __builtin_amdgcn_rcpf(1.0f + e);
    return copysignf(r, x);
}

// per-lane x chunk: row m, i = 8g..8g+7 (tail-masked; no OOB reads)
__device__ __forceinline__ void load_x(const float* p, int g, float4& a, float4& b) {
    a = *(const float4*)p;
    if (g < 3) {
        b = *(const float4*)(p + 4);
    } else {
        b.x = p[4];            // i = 28
        b.y = 0.f; b.z = 0.f; b.w = 0.f;
    }
}

#define MFMA16(A, B, C) __builtin_amdgcn_mfma_f32_16x16x32_f16((A), (B), (C), 0, 0, 0)

// step body: reads planes[CUR], writes planes[CUR^1]; X0/X1 hold x_t and are
// reloaded with x_{t+2} right after conversion (ping-pong, depth-2 prefetch)
#define STEP(CUR, X0, X1, TV)                                                 \
  {                                                                           \
    f16x8 bx;                                                                 \
    bx[0] = (_Float16)X0.x; bx[1] = (_Float16)X0.y;                           \
    bx[2] = (_Float16)X0.z; bx[3] = (_Float16)X0.w;                           \
    bx[4] = (_Float16)X1.x; bx[5] = (_Float16)X1.y;                           \
    bx[6] = (_Float16)X1.z; bx[7] = (_Float16)X1.w;                           \
    if ((TV) + 2 < TT) load_x(xrow + ((TV) + 2) * NI, g, X0, X1);             \
    f16x8 Bhi[4], Blo[4];                                                     \
    _Pragma("unroll") for (int s = 0; s < 4; ++s)                             \
      Bhi[s] = *(const f16x8*)&planes[CUR][0][m][32 * s + 8 * g];             \
    _Pragma("unroll") for (int s = 0; s < 4; ++s)                             \
      Blo[s] = *(const f16x8*)&planes[CUR][1][m][32 * s + 8 * g];             \
    f32x4 c0 = {0.f,0.f,0.f,0.f}, c1 = {0.f,0.f,0.f,0.f};                     \
    f32x4 c2 = {0.f,0.f,0.f,0.f}, c3 = {0.f,0.f,0.f,0.f};                     \
    c0 = MFMA16(Aw[4], bx, c0);                                               \
    c1 = MFMA16(Aw[1], Bhi[1], c1);                                           \
    c2 = MFMA16(Aw[2], Bhi[2], c2);                                           \
    c3 = MFMA16(Aw[3], Bhi[3], c3);                                           \
    c0 = MFMA16(Aw[0], Bhi[0], c0);                                           \
    c1 = MFMA16(Aw[1], Blo[1], c1);                                           \
    c2 = MFMA16(Aw[2], Blo[2], c2);                                           \
    c3 = MFMA16(Aw[3], Blo[3], c3);                                           \
    c0 = MFMA16(Aw[0], Blo[0], c0);                                           \
    if (IS_DEC && fcw >= 0 && (TV) > 0) {                                     \
      f32x4 f0 = {0.f,0.f,0.f,0.f}, f1 = {0.f,0.f,0.f,0.f};                   \
      f0 = MFMA16(Afc[0], Bhi[0], f0);                                        \
      f1 = MFMA16(Afc[1], Bhi[1], f1);                                        \
      f0 = MFMA16(Afc[2], Bhi[2], f0);                                        \
      f1 = MFMA16(Afc[3], Bhi[3], f1);                                        \
      _Pragma("unroll") for (int q = 0; q < 4; ++q) {                         \
        int c = 16 * fcw + 4 * g + q;                                         \
        if (c < NC)                                                           \
          out[((long)(b0 + m) * TT + ((TV) - 1)) * NC + c] =                  \
              f0[q] + f1[q] + fcbv[q];                                        \
      }                                                                       \
    }                                                                         \
    f16x4 hhi, hlo;                                                           \
    _Pragma("unroll") for (int q = 0; q < 4; ++q) {                           \
      float hv = fast_tanh(c0[q] + c1[q] + c2[q] + c3[q] + bias[q]);          \
      _Float16 hh = (_Float16)hv;                                             \
      hhi[q] = hh;                                                            \
      hlo[q] = (_Float16)(hv - (float)hh);                                    \
    }                                                                         \
    *(f16x4*)&planes[CUR ^ 1][0][m][16 * w + 4 * g] = hhi;                    \
    *(f16x4*)&planes[CUR ^ 1][1][m][16 * w + 4 * g] = hlo;                    \
    __syncthreads();                                                          \
  }

// MFMA 16x16x32 layouts (m89/m91-verified):
//   A[m][k]: m = lane&15, k = (lane>>4)*8 + e
//   B[k][n]: n = lane&15, k = (lane>>4)*8 + e
//   C/D:     col = lane&15, row = (lane>>4)*4 + reg
// We compute W[j,160] @ Hcat^T[160,b]: A rows = j, B cols = batch row.
template <int IS_DEC>
__launch_bounds__(512, 1)
__global__ void rnn_mfma(const float* __restrict__ xin,   // [B,T,NI]
                         const float* __restrict__ h0p, long h0s,
                         const float* __restrict__ Wih,   // [H,NI]
                         const float* __restrict__ Whh,   // [H,H]
                         const float* __restrict__ bih,
                         const float* __restrict__ bhh,
                         const float* __restrict__ fcW,   // [NC,H]
                         const float* __restrict__ fcb,
                         float* __restrict__ out)
{
    __shared__ __align__(16) _Float16 planes[2][2][ROWS][PSTR]; // [dbuf][hi/lo][b][i]

    const int tid  = threadIdx.x;
    const int lane = tid & 63;
    const int w    = tid >> 6;          // wave = j-tile 0..7
    const int m    = lane & 15;
    const int g    = lane >> 4;         // 0..3
    const int b0   = blockIdx.x * ROWS;

    // ---- A fragments: rows j = 16w + m of [Whh | Wih], fp16, resident all steps ----
    const int jr = 16 * w + m;
    f16x8 Aw[5];
#pragma unroll
    for (int s = 0; s < 4; ++s) {
        const float* src = Whh + jr * HH + 32 * s + 8 * g;
        float4 v0 = *(const float4*)src;
        float4 v1 = *(const float4*)(src + 4);
        f16x8 a;
        a[0] = (_Float16)v0.x; a[1] = (_Float16)v0.y;
        a[2] = (_Float16)v0.z; a[3] = (_Float16)v0.w;
        a[4] = (_Float16)v1.x; a[5] = (_Float16)v1.y;
        a[6] = (_Float16)v1.z; a[7] = (_Float16)v1.w;
        Aw[s] = a;
    }
    {
        f16x8 a;
#pragma unroll
        for (int e = 0; e < 8; ++e) {
            int i = 8 * g + e;
            float v = (i < NI) ? Wih[jr * NI + i] : 0.f;
            a[e] = (_Float16)v;
        }
        Aw[4] = a;
    }
    float bias[4];
#pragma unroll
    for (int q = 0; q < 4; ++q)
        bias[q] = bih[16 * w + 4 * g + q] + bhh[16 * w + 4 * g + q];

    // ---- FC A fragments (decoder, waves 6 & 7 handle c-tiles 0 & 1) ----
    const int fcw = w - 6;
    f16x8 Afc[4];
    float fcbv[4];
    if (IS_DEC && fcw >= 0) {
        int c = 16 * fcw + m;
#pragma unroll
        for (int s = 0; s < 4; ++s) {
            f16x8 a;
#pragma unroll
            for (int e = 0; e < 8; ++e) {
                int k = 32 * s + 8 * g + e;
                a[e] = (c < NC) ? (_Float16)fcW[c * HH + k] : (_Float16)0.f;
            }
            Afc[s] = a;
        }
#pragma unroll
        for (int q = 0; q < 4; ++q) {
            int c2 = 16 * fcw + 4 * g + q;
            fcbv[q] = (c2 < NC) ? fcb[c2] : 0.f;
        }
    }

    // ---- h0 -> planes[0] (split hi/lo fp16) ----
    {
        int b  = (tid * 4) >> 7;
        int i0 = (tid * 4) & 127;
        const float* hr = h0p + (long)(b0 + b) * h0s + i0;
        float4 v = *(const float4*)hr;
        float vv[4] = {v.x, v.y, v.z, v.w};
        f16x4 hi, lo;
#pragma unroll
        for (int e = 0; e < 4; ++e) {
            _Float16 h = (_Float16)vv[e];
            hi[e] = h;
            lo[e] = (_Float16)(vv[e] - (float)h);
        }
        *(f16x4*)&planes[0][0][b][i0] = hi;
        *(f16x4*)&planes[0][1][b][i0] = lo;
    }

    // ---- x prefetch: per-lane chunk of rows, depth 2 (ping-pong) ----
    const float* xrow = xin + ((long)(b0 + m) * TT) * NI + 8 * g;
    float4 xa0, xa1, xb0, xb1;
    load_x(xrow + 0 * NI, g, xa0, xa1);
    load_x(xrow + 1 * NI, g, xb0, xb1);

    __syncthreads();

    for (int t = 0; t < TT; t += 2) {
        STEP(0, xa0, xa1, t);
        STEP(1, xb0, xb1, t + 1);
    }

    if (IS_DEC) {
        // final FC for t = TT-1 (h_T is in planes[0], TT even)
        if (fcw >= 0) {
            f16x8 Bh[4];
#pragma unroll
            for (int s = 0; s < 4; ++s)
                Bh[s] = *(const f16x8*)&planes[0][0][m][32 * s + 8 * g];
            f32x4 f0 = {0.f,0.f,0.f,0.f}, f1 = {0.f,0.f,0.f,0.f};
            f0 = MFMA16(Afc[0], Bh[0], f0);
            f1 = MFMA16(Afc[1], Bh[1], f1);
            f0 = MFMA16(Afc[2], Bh[2], f0);
            f1 = MFMA16(Afc[3], Bh[3], f1);
#pragma unroll
            for (int q = 0; q < 4; ++q) {
                int c = 16 * fcw + 4 * g + q;
                if (c < NC)
                    out[((long)(b0 + m) * TT + (TT - 1)) * NC + c] =
                        f0[q] + f1[q] + fcbv[q];
            }
        }
    } else {
        // stash h_T (fp32) into first 128 floats of each row's out region
        int b  = (tid * 4) >> 7;
        int i0 = (tid * 4) & 127;
        float4 v;
        v.x = (float)planes[0][0][b][i0 + 0] + (float)planes[0][1][b][i0 + 0];
        v.y = (float)planes[0][0][b][i0 + 1] + (float)planes[0][1][b][i0 + 1];
        v.z = (float)planes[0][0][b][i0 + 2] + (float)planes[0][1][b][i0 + 2];
        v.w = (float)planes[0][0][b][i0 + 3] + (float)planes[0][1][b][i0 + 3];
        *(float4*)(out + (long)(b0 + b) * TT * NC + i0) = v;
    }
}

extern "C" void kernel_launch(void* const* d_in, const int* in_sizes, int n_in,
                              void* d_out, int out_size, void* d_ws, size_t ws_size,
                              hipStream_t stream) {
    const float* enc_in  = (const float*)d_in[0];
    const float* enc_h0  = (const float*)d_in[1];
    const float* dec_in  = (const float*)d_in[2];
    const float* enc_Wih = (const float*)d_in[3];
    const float* enc_Whh = (const float*)d_in[4];
    const float* enc_bih = (const float*)d_in[5];
    const float* enc_bhh = (const float*)d_in[6];
    const float* dec_Wih = (const float*)d_in[7];
    const float* dec_Whh = (const float*)d_in[8];
    const float* dec_bih = (const float*)d_in[9];
    const float* dec_bhh = (const float*)d_in[10];
    const float* fc_W    = (const float*)d_in[11];
    const float* fc_b    = (const float*)d_in[12];
    float* out = (float*)d_out;

    dim3 grid(2048 / ROWS), block(512);

    rnn_mfma<0><<<grid, block, 0, stream>>>(enc_in, enc_h0, (long)HH,
                                            enc_Wih, enc_Whh, enc_bih, enc_bhh,
                                            nullptr, nullptr, out);
    rnn_mfma<1><<<grid, block, 0, stream>>>(dec_in, out, (long)TT * NC,
                                            dec_Wih, dec_Whh, dec_bih, dec_bhh,
                                            fc_W, fc_b, out);
}

// Round 4
// 506.627 us; speedup vs baseline: 1.2043x; 1.2043x over previous
//
#include <hip/hip_runtime.h>
#include <math.h>

#define TT 256
#define NI 29
#define HH 128
#define NC 29
#define ROWS 16
#define PSTR 136   // fp16 plane stride (halfs): 272B rows, b128 reads hit floor rounds
#define BBATCH 2048L
#define WS_NEED (BBATCH * TT * HH * 2)   // 134,217,728 B: xp fp16 [B*T][H]

typedef _Float16 f16x8 __attribute__((ext_vector_type(8)));
typedef _Float16 f16x4 __attribute__((ext_vector_type(4)));
typedef float f32x4 __attribute__((ext_vector_type(4)));

__device__ __forceinline__ float fast_tanh(float x) {
    float ax = fabsf(x);
    float e = __builtin_amdgcn_exp2f(ax * -2.885390081777927f);
    float r = (1.0f - e) * __builtin_amdgcn_rcpf(1.0f + e);
    return copysignf(r, x);
}

// per-lane 8-float chunk of a 29-float row, i = 8g..8g+7 (tail-masked, no OOB)
__device__ __forceinline__ void load_x(const float* p, int g, float4& a, float4& b) {
    a = *(const float4*)p;
    if (g < 3) {
        b = *(const float4*)(p + 4);
    } else {
        b.x = p[4];            // i = 28
        b.y = 0.f; b.z = 0.f; b.w = 0.f;
    }
}

__device__ __forceinline__ f16x8 cvt8(const float4& a, const float4& b) {
    f16x8 r;
    r[0] = (_Float16)a.x; r[1] = (_Float16)a.y;
    r[2] = (_Float16)a.z; r[3] = (_Float16)a.w;
    r[4] = (_Float16)b.x; r[5] = (_Float16)b.y;
    r[6] = (_Float16)b.z; r[7] = (_Float16)b.w;
    return r;
}

#define MFMA16(A, B, C) __builtin_amdgcn_mfma_f32_16x16x32_f16((A), (B), (C), 0, 0, 0)

// ---------------------------------------------------------------------------
// xp kernel: xp[bt][j] = sum_k x[bt][k] * Wih[j][k]   (fp16 out, bias NOT folded)
// A = Wih tile [16j x 32k], B = x^T [32k x 16bt]; C col = bt (lane&15), row = j.
// ---------------------------------------------------------------------------
__launch_bounds__(256)
__global__ void xp_kernel(const float* __restrict__ x,     // [B*T, NI]
                          const float* __restrict__ Wih,   // [H, NI]
                          _Float16* __restrict__ xp)       // [B*T, H]
{
    const int tid  = threadIdx.x;
    const int lane = tid & 63;
    const int wv   = tid >> 6;
    const int m    = lane & 15;
    const int g    = lane >> 4;
    const long bt0 = ((long)blockIdx.x * 4 + wv) * 16;

    // A fragments: Wih rows j = 16*jt + m, k = 8g..8g+7 (zero-padded past NI)
    f16x8 A[8];
#pragma unroll
    for (int jt = 0; jt < 8; ++jt) {
        float4 v0, v1;
        load_x(Wih + (16 * jt + m) * NI + 8 * g, g, v0, v1);
        A[jt] = cvt8(v0, v1);
    }
    // B fragment: x row bt0+m, k = 8g..8g+7
    float4 u0, u1;
    load_x(x + (bt0 + m) * NI + 8 * g, g, u0, u1);
    f16x8 Bx = cvt8(u0, u1);

    f32x4 z = {0.f, 0.f, 0.f, 0.f};
    f32x4 acc[8];
#pragma unroll
    for (int jt = 0; jt < 8; ++jt)
        acc[jt] = MFMA16(A[jt], Bx, z);

#pragma unroll
    for (int jt = 0; jt < 8; ++jt) {
        f16x4 o;
        o[0] = (_Float16)acc[jt][0];
        o[1] = (_Float16)acc[jt][1];
        o[2] = (_Float16)acc[jt][2];
        o[3] = (_Float16)acc[jt][3];
        *(f16x4*)(xp + (bt0 + m) * HH + 16 * jt + 4 * g) = o;
    }
}

// ---------------------------------------------------------------------------
// Recurrent kernel. planes[dbuf][b][j] single fp16 h plane.
// Raw s_barrier + lgkmcnt(0) only: no vmcnt drain -> xp prefetch stays in
// flight, FC stores fire-and-forget. Double-buffer makes 1 barrier/step safe:
// each wave's reads of planes[cur] are complete (consumed by MFMA) before it
// reaches the barrier; writes go to planes[nxt] and are acked by lgkmcnt(0).
// ---------------------------------------------------------------------------
#define STEP(CUR, XQ, X0, X1, TV)                                             \
  {                                                                           \
    f16x4 nx = {(_Float16)0, (_Float16)0, (_Float16)0, (_Float16)0};          \
    if (USE_XP) {                                                             \
      if ((TV) + 2 < TT) nx = *(const f16x4*)(xpro + ((TV) + 2) * HH);        \
    }                                                                         \
    f16x8 bx;                                                                 \
    if (!USE_XP) {                                                            \
      bx = cvt8(X0, X1);                                                      \
      if ((TV) + 2 < TT) load_x(xrow + ((TV) + 2) * NI, g, X0, X1);           \
    }                                                                         \
    f16x8 Bh[4];                                                              \
    _Pragma("unroll") for (int s = 0; s < 4; ++s)                             \
      Bh[s] = *(const f16x8*)&planes[CUR][m][32 * s + 8 * g];                 \
    f32x4 c0 = {0.f,0.f,0.f,0.f}, c1 = {0.f,0.f,0.f,0.f};                     \
    if (!USE_XP) c0 = MFMA16(Aw4, bx, c0);                                    \
    c0 = MFMA16(Aw[0], Bh[0], c0);                                            \
    c1 = MFMA16(Aw[1], Bh[1], c1);                                            \
    c0 = MFMA16(Aw[2], Bh[2], c0);                                            \
    c1 = MFMA16(Aw[3], Bh[3], c1);                                            \
    if (IS_DEC && fcw >= 0 && (TV) > 0) {                                     \
      f32x4 f0 = {0.f,0.f,0.f,0.f}, f1 = {0.f,0.f,0.f,0.f};                   \
      f0 = MFMA16(Afc[0], Bh[0], f0);                                         \
      f1 = MFMA16(Afc[1], Bh[1], f1);                                         \
      f0 = MFMA16(Afc[2], Bh[2], f0);                                         \
      f1 = MFMA16(Afc[3], Bh[3], f1);                                         \
      _Pragma("unroll") for (int q = 0; q < 4; ++q) {                         \
        int c = 16 * fcw + 4 * g + q;                                         \
        if (c < NC)                                                           \
          out[((long)(b0 + m) * TT + ((TV) - 1)) * NC + c] =                  \
              f0[q] + f1[q] + fcbv[q];                                        \
      }                                                                       \
    }                                                                         \
    f16x4 hhi;                                                                \
    _Pragma("unroll") for (int q = 0; q < 4; ++q) {                           \
      float aq = c0[q] + c1[q] + bias[q];                                     \
      if (USE_XP) aq += (float)XQ[q];                                         \
      hhi[q] = (_Float16)fast_tanh(aq);                                       \
    }                                                                         \
    *(f16x4*)&planes[CUR ^ 1][m][16 * w + 4 * g] = hhi;                       \
    asm volatile("s_waitcnt lgkmcnt(0)" ::: "memory");                        \
    __builtin_amdgcn_s_barrier();                                             \
    __builtin_amdgcn_sched_barrier(0);                                        \
    XQ = nx;                                                                  \
  }

// MFMA 16x16x32 layouts (m89/m91; confirmed end-to-end by R2 pass):
//   A[m][k]: m = lane&15, k = (lane>>4)*8 + e
//   B[k][n]: n = lane&15, k = (lane>>4)*8 + e
//   C/D:     col = lane&15, row = (lane>>4)*4 + reg
template <int IS_DEC, int USE_XP>
__launch_bounds__(512, 1)
__global__ void rnn_mfma(const float* __restrict__ xin,       // [B,T,NI] (fallback)
                         const _Float16* __restrict__ xp,     // [B*T,H] (fast)
                         const float* __restrict__ h0p, long h0s,
                         const float* __restrict__ Wih,       // (fallback)
                         const float* __restrict__ Whh,       // [H,H]
                         const float* __restrict__ bih,
                         const float* __restrict__ bhh,
                         const float* __restrict__ fcW,       // [NC,H]
                         const float* __restrict__ fcb,
                         float* __restrict__ out)
{
    __shared__ __align__(16) _Float16 planes[2][ROWS][PSTR];

    const int tid  = threadIdx.x;
    const int lane = tid & 63;
    const int w    = tid >> 6;          // wave = j-tile 0..7
    const int m    = lane & 15;
    const int g    = lane >> 4;         // 0..3
    const int b0   = blockIdx.x * ROWS;

    // ---- A fragments: rows j = 16w + m of Whh, fp16, resident all steps ----
    const int jr = 16 * w + m;
    f16x8 Aw[4];
#pragma unroll
    for (int s = 0; s < 4; ++s) {
        const float* src = Whh + jr * HH + 32 * s + 8 * g;
        float4 v0 = *(const float4*)src;
        float4 v1 = *(const float4*)(src + 4);
        Aw[s] = cvt8(v0, v1);
    }
    f16x8 Aw4;
    if (!USE_XP) {
        float4 v0, v1;
        load_x(Wih + jr * NI + 8 * g, g, v0, v1);
        Aw4 = cvt8(v0, v1);
    }
    float bias[4];
#pragma unroll
    for (int q = 0; q < 4; ++q)
        bias[q] = bih[16 * w + 4 * g + q] + bhh[16 * w + 4 * g + q];

    // ---- FC A fragments (decoder, waves 6 & 7 -> c-tiles 0 & 1) ----
    const int fcw = w - 6;
    f16x8 Afc[4];
    float fcbv[4] = {0.f, 0.f, 0.f, 0.f};
    if (IS_DEC && fcw >= 0) {
        int c = 16 * fcw + m;
#pragma unroll
        for (int s = 0; s < 4; ++s) {
            f16x8 a;
#pragma unroll
            for (int e = 0; e < 8; ++e) {
                int k = 32 * s + 8 * g + e;
                a[e] = (c < NC) ? (_Float16)fcW[c * HH + k] : (_Float16)0.f;
            }
            Afc[s] = a;
        }
#pragma unroll
        for (int q = 0; q < 4; ++q) {
            int c2 = 16 * fcw + 4 * g + q;
            fcbv[q] = (c2 < NC) ? fcb[c2] : 0.f;
        }
    }

    // ---- h0 -> planes[0] (fp16) ----
    {
        int b  = tid >> 5;              // 0..15
        int i0 = (tid & 31) * 4;        // 0..124
        const float* hr = h0p + (long)(b0 + b) * h0s + i0;
        float4 v = *(const float4*)hr;
        f16x4 hq;
        hq[0] = (_Float16)v.x; hq[1] = (_Float16)v.y;
        hq[2] = (_Float16)v.z; hq[3] = (_Float16)v.w;
        *(f16x4*)&planes[0][b][i0] = hq;
    }

    // ---- x / xp prefetch (depth 2, ping-pong) ----
    const _Float16* xpro = xp + ((long)(b0 + m) * TT) * HH + 16 * w + 4 * g;
    const float*    xrow = xin + ((long)(b0 + m) * TT) * NI + 8 * g;
    f16x4 xqa = {(_Float16)0, (_Float16)0, (_Float16)0, (_Float16)0};
    f16x4 xqb = xqa;
    float4 xa0, xa1, xb0, xb1;
    if (USE_XP) {
        xqa = *(const f16x4*)(xpro);
        xqb = *(const f16x4*)(xpro + HH);
    } else {
        load_x(xrow + 0 * NI, g, xa0, xa1);
        load_x(xrow + 1 * NI, g, xb0, xb1);
    }
    __syncthreads();

    for (int t = 0; t < TT; t += 2) {
        STEP(0, xqa, xa0, xa1, t);
        STEP(1, xqb, xb0, xb1, t + 1);
    }

    if (IS_DEC) {
        // final FC for t = TT-1 (h_{T-1} is in planes[0], TT even)
        if (fcw >= 0) {
            f16x8 Bh[4];
#pragma unroll
            for (int s = 0; s < 4; ++s)
                Bh[s] = *(const f16x8*)&planes[0][m][32 * s + 8 * g];
            f32x4 f0 = {0.f,0.f,0.f,0.f}, f1 = {0.f,0.f,0.f,0.f};
            f0 = MFMA16(Afc[0], Bh[0], f0);
            f1 = MFMA16(Afc[1], Bh[1], f1);
            f0 = MFMA16(Afc[2], Bh[2], f0);
            f1 = MFMA16(Afc[3], Bh[3], f1);
#pragma unroll
            for (int q = 0; q < 4; ++q) {
                int c = 16 * fcw + 4 * g + q;
                if (c < NC)
                    out[((long)(b0 + m) * TT + (TT - 1)) * NC + c] =
                        f0[q] + f1[q] + fcbv[q];
            }
        }
    } else {
        // stash h_T (fp32) into first 128 floats of each row's out region;
        // decoder reads it in its prologue, FC pass overwrites every element.
        int b  = tid >> 5;
        int i0 = (tid & 31) * 4;
        float4 v;
        v.x = (float)planes[0][b][i0 + 0];
        v.y = (float)planes[0][b][i0 + 1];
        v.z = (float)planes[0][b][i0 + 2];
        v.w = (float)planes[0][b][i0 + 3];
        *(float4*)(out + (long)(b0 + b) * TT * NC + i0) = v;
    }
}

extern "C" void kernel_launch(void* const* d_in, const int* in_sizes, int n_in,
                              void* d_out, int out_size, void* d_ws, size_t ws_size,
                              hipStream_t stream) {
    const float* enc_in  = (const float*)d_in[0];
    const float* enc_h0  = (const float*)d_in[1];
    const float* dec_in  = (const float*)d_in[2];
    const float* enc_Wih = (const float*)d_in[3];
    const float* enc_Whh = (const float*)d_in[4];
    const float* enc_bih = (const float*)d_in[5];
    const float* enc_bhh = (const float*)d_in[6];
    const float* dec_Wih = (const float*)d_in[7];
    const float* dec_Whh = (const float*)d_in[8];
    const float* dec_bih = (const float*)d_in[9];
    const float* dec_bhh = (const float*)d_in[10];
    const float* fc_W    = (const float*)d_in[11];
    const float* fc_b    = (const float*)d_in[12];
    float* out = (float*)d_out;

    dim3 grid(BBATCH / ROWS), block(512);
    const bool fast = (ws_size >= (size_t)WS_NEED);

    if (fast) {
        _Float16* xp = (_Float16*)d_ws;
        dim3 xgrid((unsigned)(BBATCH * TT / 64)), xblock(256);
        xp_kernel<<<xgrid, xblock, 0, stream>>>(enc_in, enc_Wih, xp);
        rnn_mfma<0, 1><<<grid, block, 0, stream>>>(enc_in, xp, enc_h0, (long)HH,
                                                   enc_Wih, enc_Whh, enc_bih, enc_bhh,
                                                   nullptr, nullptr, out);
        xp_kernel<<<xgrid, xblock, 0, stream>>>(dec_in, dec_Wih, xp);
        rnn_mfma<1, 1><<<grid, block, 0, stream>>>(dec_in, xp, out, (long)TT * NC,
                                                   dec_Wih, dec_Whh, dec_bih, dec_bhh,
                                                   fc_W, fc_b, out);
    } else {
        rnn_mfma<0, 0><<<grid, block, 0, stream>>>(enc_in, nullptr, enc_h0, (long)HH,
                                                   enc_Wih, enc_Whh, enc_bih, enc_bhh,
                                                   nullptr, nullptr, out);
        rnn_mfma<1, 0><<<grid, block, 0, stream>>>(dec_in, nullptr, out, (long)TT * NC,
                                                   dec_Wih, dec_Whh, dec_bih, dec_bhh,
                                                   fc_W, fc_b, out);
    }
}

// Round 5
// 472.232 us; speedup vs baseline: 1.2921x; 1.0728x over previous
//
#include <hip/hip_runtime.h>
#include <math.h>

#define TT 256
#define NI 29
#define HH 128
#define NC 29
#define ROWS 16
#define PSTR 136   // fp16 plane stride (halfs): 272 B rows
#define BBATCH 2048L
#define WS_NEED (BBATCH * TT * HH * 2)   // 134,217,728 B: xp fp16 [B*T][H]

typedef _Float16 f16x8 __attribute__((ext_vector_type(8)));
typedef _Float16 f16x4 __attribute__((ext_vector_type(4)));
typedef float f32x4 __attribute__((ext_vector_type(4)));

// tanh(x) = 1 - 2/(e^{2x}+1);  e^{2x} = 2^{2x*log2(e)}.  5 ops, no sign fixup.
// Large |x| degrades gracefully (exp2 -> inf/0 -> +-1).
__device__ __forceinline__ float fast_tanh(float x) {
    float e = __builtin_amdgcn_exp2f(x * 2.885390081777927f);
    return 1.0f - 2.0f * __builtin_amdgcn_rcpf(e + 1.0f);
}

// per-lane 8-float chunk of a 29-float row, i = 8g..8g+7 (tail-masked, no OOB)
__device__ __forceinline__ void load_x(const float* p, int g, float4& a, float4& b) {
    a = *(const float4*)p;
    if (g < 3) {
        b = *(const float4*)(p + 4);
    } else {
        b.x = p[4];            // i = 28
        b.y = 0.f; b.z = 0.f; b.w = 0.f;
    }
}

__device__ __forceinline__ f16x8 cvt8(const float4& a, const float4& b) {
    f16x8 r;
    r[0] = (_Float16)a.x; r[1] = (_Float16)a.y;
    r[2] = (_Float16)a.z; r[3] = (_Float16)a.w;
    r[4] = (_Float16)b.x; r[5] = (_Float16)b.y;
    r[6] = (_Float16)b.z; r[7] = (_Float16)b.w;
    return r;
}

#define MFMA16(A, B, C) __builtin_amdgcn_mfma_f32_16x16x32_f16((A), (B), (C), 0, 0, 0)

// ---------------------------------------------------------------------------
// xp kernel: xp[bt][j] = sum_k x[bt][k] * Wih[j][k]   (fp16, bias not folded)
// ---------------------------------------------------------------------------
__launch_bounds__(256)
__global__ void xp_kernel(const float* __restrict__ x,     // [B*T, NI]
                          const float* __restrict__ Wih,   // [H, NI]
                          _Float16* __restrict__ xp)       // [B*T, H]
{
    const int tid  = threadIdx.x;
    const int lane = tid & 63;
    const int wv   = tid >> 6;
    const int m    = lane & 15;
    const int g    = lane >> 4;
    const long bt0 = ((long)blockIdx.x * 4 + wv) * 16;

    f16x8 A[8];
#pragma unroll
    for (int jt = 0; jt < 8; ++jt) {
        float4 v0, v1;
        load_x(Wih + (16 * jt + m) * NI + 8 * g, g, v0, v1);
        A[jt] = cvt8(v0, v1);
    }
    float4 u0, u1;
    load_x(x + (bt0 + m) * NI + 8 * g, g, u0, u1);
    f16x8 Bx = cvt8(u0, u1);

    f32x4 z = {0.f, 0.f, 0.f, 0.f};
    f32x4 acc[8];
#pragma unroll
    for (int jt = 0; jt < 8; ++jt)
        acc[jt] = MFMA16(A[jt], Bx, z);

#pragma unroll
    for (int jt = 0; jt < 8; ++jt) {
        f16x4 o;
        o[0] = (_Float16)acc[jt][0];
        o[1] = (_Float16)acc[jt][1];
        o[2] = (_Float16)acc[jt][2];
        o[3] = (_Float16)acc[jt][3];
        *(f16x4*)(xp + (bt0 + m) * HH + 16 * jt + 4 * g) = o;
    }
}

// ---------------------------------------------------------------------------
// Recurrent kernel: 4 waves, wave w owns j in [32w, 32w+32) (2 MFMA j-tiles).
// Raw s_barrier + lgkmcnt(0): no vmcnt drain -> depth-4 x prefetch stays in
// flight across steps; FC stores fire-and-forget.
// MFMA 16x16x32 layouts (m89/m91; confirmed end-to-end by R2/R4 passes):
//   A[m][k]: m = lane&15, k = (lane>>4)*8 + e
//   B[k][n]: n = lane&15, k = (lane>>4)*8 + e
//   C/D:     col = lane&15, row = (lane>>4)*4 + reg
// ---------------------------------------------------------------------------
#define STEP(CUR, XQA, XQB, XFA, XFB, TV)                                     \
  {                                                                           \
    f16x8 Bh0 = *(const f16x8*)&planes[CUR][m][ 0 + 8 * g];                   \
    f16x8 Bh1 = *(const f16x8*)&planes[CUR][m][32 + 8 * g];                   \
    f16x8 Bh2 = *(const f16x8*)&planes[CUR][m][64 + 8 * g];                   \
    f16x8 Bh3 = *(const f16x8*)&planes[CUR][m][96 + 8 * g];                   \
    f32x4 c00 = {0.f,0.f,0.f,0.f}, c01 = {0.f,0.f,0.f,0.f};                   \
    f32x4 c10 = {0.f,0.f,0.f,0.f}, c11 = {0.f,0.f,0.f,0.f};                   \
    if (!USE_XP) {                                                            \
      f16x8 bx = cvt8(XFA, XFB);                                              \
      c00 = MFMA16(AwX0, bx, c00);                                            \
      c10 = MFMA16(AwX1, bx, c10);                                            \
      if ((TV) + 4 < TT) load_x(xrow + ((TV) + 4) * NI, g, XFA, XFB);         \
    }                                                                         \
    c00 = MFMA16(Aw0[0], Bh0, c00);  c10 = MFMA16(Aw1[0], Bh0, c10);          \
    c01 = MFMA16(Aw0[1], Bh1, c01);  c11 = MFMA16(Aw1[1], Bh1, c11);          \
    c00 = MFMA16(Aw0[2], Bh2, c00);  c10 = MFMA16(Aw1[2], Bh2, c10);          \
    c01 = MFMA16(Aw0[3], Bh3, c01);  c11 = MFMA16(Aw1[3], Bh3, c11);          \
    if (IS_DEC && w < 2 && (TV) > 0) {                                        \
      f32x4 f0 = {0.f,0.f,0.f,0.f}, f1 = {0.f,0.f,0.f,0.f};                   \
      f0 = MFMA16(Afc[0], Bh0, f0);                                           \
      f1 = MFMA16(Afc[1], Bh1, f1);                                           \
      f0 = MFMA16(Afc[2], Bh2, f0);                                           \
      f1 = MFMA16(Afc[3], Bh3, f1);                                           \
      _Pragma("unroll") for (int q = 0; q < 4; ++q) {                         \
        int c = 16 * w + 4 * g + q;                                           \
        if (c < NC)                                                           \
          out[((long)(b0 + m) * TT + ((TV) - 1)) * NC + c] =                  \
              f0[q] + f1[q] + fcbv[q];                                        \
      }                                                                       \
    }                                                                         \
    f16x4 hn0, hn1;                                                           \
    _Pragma("unroll") for (int q = 0; q < 4; ++q) {                           \
      float a0 = c00[q] + c01[q] + bias0[q];                                  \
      float a1 = c10[q] + c11[q] + bias1[q];                                  \
      if (USE_XP) { a0 += (float)XQA[q]; a1 += (float)XQB[q]; }               \
      hn0[q] = (_Float16)fast_tanh(a0);                                       \
      hn1[q] = (_Float16)fast_tanh(a1);                                       \
    }                                                                         \
    if (USE_XP && (TV) + 4 < TT) {                                            \
      XQA = *(const f16x4*)(xpro + ((TV) + 4) * HH);                          \
      XQB = *(const f16x4*)(xpro + ((TV) + 4) * HH + 16);                     \
    }                                                                         \
    *(f16x4*)&planes[CUR ^ 1][m][32 * w + 4 * g]      = hn0;                  \
    *(f16x4*)&planes[CUR ^ 1][m][32 * w + 16 + 4 * g] = hn1;                  \
    asm volatile("s_waitcnt lgkmcnt(0)" ::: "memory");                        \
    __builtin_amdgcn_s_barrier();                                             \
    __builtin_amdgcn_sched_barrier(0);                                        \
  }

template <int IS_DEC, int USE_XP>
__launch_bounds__(256, 1)
__global__ void rnn_mfma(const float* __restrict__ xin,       // [B,T,NI] (fallback)
                         const _Float16* __restrict__ xp,     // [B*T,H] (fast)
                         const float* __restrict__ h0p, long h0s,
                         const float* __restrict__ Wih,
                         const float* __restrict__ Whh,       // [H,H]
                         const float* __restrict__ bih,
                         const float* __restrict__ bhh,
                         const float* __restrict__ fcW,       // [NC,H]
                         const float* __restrict__ fcb,
                         float* __restrict__ out)
{
    __shared__ __align__(16) _Float16 planes[2][ROWS][PSTR];

    const int tid  = threadIdx.x;
    const int lane = tid & 63;
    const int w    = tid >> 6;          // wave 0..3, j-range [32w, 32w+32)
    const int m    = lane & 15;
    const int g    = lane >> 4;         // 0..3
    const int b0   = blockIdx.x * ROWS;

    // ---- A fragments: Whh rows 32w+m (tile 0) and 32w+16+m (tile 1) ----
    f16x8 Aw0[4], Aw1[4];
#pragma unroll
    for (int s = 0; s < 4; ++s) {
        const float* s0 = Whh + (32 * w + m) * HH + 32 * s + 8 * g;
        const float* s1 = Whh + (32 * w + 16 + m) * HH + 32 * s + 8 * g;
        float4 v0 = *(const float4*)s0;
        float4 v1 = *(const float4*)(s0 + 4);
        Aw0[s] = cvt8(v0, v1);
        float4 u0 = *(const float4*)s1;
        float4 u1 = *(const float4*)(s1 + 4);
        Aw1[s] = cvt8(u0, u1);
    }
    f16x8 AwX0, AwX1;
    if (!USE_XP) {
        float4 v0, v1;
        load_x(Wih + (32 * w + m) * NI + 8 * g, g, v0, v1);
        AwX0 = cvt8(v0, v1);
        load_x(Wih + (32 * w + 16 + m) * NI + 8 * g, g, v0, v1);
        AwX1 = cvt8(v0, v1);
    }
    float bias0[4], bias1[4];
#pragma unroll
    for (int q = 0; q < 4; ++q) {
        int j0 = 32 * w + 4 * g + q;
        bias0[q] = bih[j0] + bhh[j0];
        bias1[q] = bih[j0 + 16] + bhh[j0 + 16];
    }

    // ---- FC A fragments (decoder, waves 0 & 1 -> c-tiles 0 & 1) ----
    f16x8 Afc[4];
    float fcbv[4] = {0.f, 0.f, 0.f, 0.f};
    if (IS_DEC && w < 2) {
        int c = 16 * w + m;
#pragma unroll
        for (int s = 0; s < 4; ++s) {
            f16x8 a;
#pragma unroll
            for (int e = 0; e < 8; ++e) {
                int k = 32 * s + 8 * g + e;
                a[e] = (c < NC) ? (_Float16)fcW[c * HH + k] : (_Float16)0.f;
            }
            Afc[s] = a;
        }
#pragma unroll
        for (int q = 0; q < 4; ++q) {
            int c2 = 16 * w + 4 * g + q;
            fcbv[q] = (c2 < NC) ? fcb[c2] : 0.f;
        }
    }

    // ---- h0 -> planes[0] (fp16): 256 threads x 8 halfs ----
    {
        int b  = tid >> 4;              // 0..15
        int i0 = (tid & 15) * 8;        // 0..120
        const float* hr = h0p + (long)(b0 + b) * h0s + i0;
        float4 v0 = *(const float4*)hr;
        float4 v1 = *(const float4*)(hr + 4);
        *(f16x8*)&planes[0][b][i0] = cvt8(v0, v1);
    }

    // ---- x / xp prefetch, depth 4 (statically named regs) ----
    const _Float16* xpro = xp + ((long)(b0 + m) * TT) * HH + 32 * w + 4 * g;
    const float*    xrow = xin + ((long)(b0 + m) * TT) * NI + 8 * g;
    f16x4 xqa0, xqb0, xqa1, xqb1, xqa2, xqb2, xqa3, xqb3;
    float4 xf0a, xf0b, xf1a, xf1b, xf2a, xf2b, xf3a, xf3b;
    if (USE_XP) {
        xqa0 = *(const f16x4*)(xpro + 0 * HH); xqb0 = *(const f16x4*)(xpro + 0 * HH + 16);
        xqa1 = *(const f16x4*)(xpro + 1 * HH); xqb1 = *(const f16x4*)(xpro + 1 * HH + 16);
        xqa2 = *(const f16x4*)(xpro + 2 * HH); xqb2 = *(const f16x4*)(xpro + 2 * HH + 16);
        xqa3 = *(const f16x4*)(xpro + 3 * HH); xqb3 = *(const f16x4*)(xpro + 3 * HH + 16);
    } else {
        load_x(xrow + 0 * NI, g, xf0a, xf0b);
        load_x(xrow + 1 * NI, g, xf1a, xf1b);
        load_x(xrow + 2 * NI, g, xf2a, xf2b);
        load_x(xrow + 3 * NI, g, xf3a, xf3b);
    }
    __syncthreads();

    for (int t = 0; t < TT; t += 4) {
        STEP(0, xqa0, xqb0, xf0a, xf0b, t);
        STEP(1, xqa1, xqb1, xf1a, xf1b, t + 1);
        STEP(0, xqa2, xqb2, xf2a, xf2b, t + 2);
        STEP(1, xqa3, xqb3, xf3a, xf3b, t + 3);
    }

    if (IS_DEC) {
        // final FC for t = TT-1 (h_{T-1} in planes[0]; TT even)
        if (w < 2) {
            f16x8 Bh0 = *(const f16x8*)&planes[0][m][ 0 + 8 * g];
            f16x8 Bh1 = *(const f16x8*)&planes[0][m][32 + 8 * g];
            f16x8 Bh2 = *(const f16x8*)&planes[0][m][64 + 8 * g];
            f16x8 Bh3 = *(const f16x8*)&planes[0][m][96 + 8 * g];
            f32x4 f0 = {0.f,0.f,0.f,0.f}, f1 = {0.f,0.f,0.f,0.f};
            f0 = MFMA16(Afc[0], Bh0, f0);
            f1 = MFMA16(Afc[1], Bh1, f1);
            f0 = MFMA16(Afc[2], Bh2, f0);
            f1 = MFMA16(Afc[3], Bh3, f1);
#pragma unroll
            for (int q = 0; q < 4; ++q) {
                int c = 16 * w + 4 * g + q;
                if (c < NC)
                    out[((long)(b0 + m) * TT + (TT - 1)) * NC + c] =
                        f0[q] + f1[q] + fcbv[q];
            }
        }
    } else {
        // stash h_T (fp32) into first 128 floats of each row's out region;
        // decoder reads it in its prologue, then FC overwrites every element.
        int b  = tid >> 4;
        int i0 = (tid & 15) * 8;
        f16x8 hv = *(const f16x8*)&planes[0][b][i0];
        float4 v0, v1;
        v0.x = (float)hv[0]; v0.y = (float)hv[1];
        v0.z = (float)hv[2]; v0.w = (float)hv[3];
        v1.x = (float)hv[4]; v1.y = (float)hv[5];
        v1.z = (float)hv[6]; v1.w = (float)hv[7];
        float* dst = out + (long)(b0 + b) * TT * NC + i0;
        *(float4*)dst = v0;
        *(float4*)(dst + 4) = v1;
    }
}

extern "C" void kernel_launch(void* const* d_in, const int* in_sizes, int n_in,
                              void* d_out, int out_size, void* d_ws, size_t ws_size,
                              hipStream_t stream) {
    const float* enc_in  = (const float*)d_in[0];
    const float* enc_h0  = (const float*)d_in[1];
    const float* dec_in  = (const float*)d_in[2];
    const float* enc_Wih = (const float*)d_in[3];
    const float* enc_Whh = (const float*)d_in[4];
    const float* enc_bih = (const float*)d_in[5];
    const float* enc_bhh = (const float*)d_in[6];
    const float* dec_Wih = (const float*)d_in[7];
    const float* dec_Whh = (const float*)d_in[8];
    const float* dec_bih = (const float*)d_in[9];
    const float* dec_bhh = (const float*)d_in[10];
    const float* fc_W    = (const float*)d_in[11];
    const float* fc_b    = (const float*)d_in[12];
    float* out = (float*)d_out;

    dim3 grid(BBATCH / ROWS), block(256);
    const bool fast = (ws_size >= (size_t)WS_NEED);

    if (fast) {
        _Float16* xp = (_Float16*)d_ws;
        dim3 xgrid((unsigned)(BBATCH * TT / 64)), xblock(256);
        xp_kernel<<<xgrid, xblock, 0, stream>>>(enc_in, enc_Wih, xp);
        rnn_mfma<0, 1><<<grid, block, 0, stream>>>(enc_in, xp, enc_h0, (long)HH,
                                                   enc_Wih, enc_Whh, enc_bih, enc_bhh,
                                                   nullptr, nullptr, out);
        xp_kernel<<<xgrid, xblock, 0, stream>>>(dec_in, dec_Wih, xp);
        rnn_mfma<1, 1><<<grid, block, 0, stream>>>(dec_in, xp, out, (long)TT * NC,
                                                   dec_Wih, dec_Whh, dec_bih, dec_bhh,
                                                   fc_W, fc_b, out);
    } else {
        rnn_mfma<0, 0><<<grid, block, 0, stream>>>(enc_in, nullptr, enc_h0, (long)HH,
                                                   enc_Wih, enc_Whh, enc_bih, enc_bhh,
                                                   nullptr, nullptr, out);
        rnn_mfma<1, 0><<<grid, block, 0, stream>>>(dec_in, nullptr, out, (long)TT * NC,
                                                   dec_Wih, dec_Whh, dec_bih, dec_bhh,
                                                   fc_W, fc_b, out);
    }
}